// Round 7
// baseline (48062.646 us; speedup 1.0000x reference)
//
#include <hip/hip_runtime.h>
#include <hip/hip_bf16.h>
#include <math.h>

// GRU_74758200754229: 2-layer GRU (B=128, T=1024, F=256, H=512) + final linear.
// v5 (4th submit; rounds 4-6 all GPUAcquisitionTimeout, never measured):
// per-step launches; 2D tiling: WG = (batch-group of 64) x (4 j, BOTH layers).
// Lane = batch. Weights fp32 in LDS (uniform b128 broadcast). State circulates
// as bf16 [b][k] global buffers; fp32 state kept separately for the z*h path.
// 64-k chunks double-buffered in LDS, k-quarter split across waves + reduction.

#define T_LEN 1024
#define B_SZ  128
#define F_IN  256
#define H_SZ  512
#define NCH   16

// LDS dword offsets
#define WL0_OFF  0        // 12 rows x 768   (Whh0 | Wih0)
#define WL1_OFF  9216     // 12 rows x 1024  (Whh1 | Wih1)
#define SBUF_OFF 21504    // 4 bufs x [64 b][36 dw]  (2 streams x 2 phases)
#define RED_OFF  30720    // [2 sL][3 part][16 acc][64 lane]
#define LDS_FLOATS 36864
#define LDS_BYTES  (LDS_FLOATS * 4)   // 147456 B <= 160 KiB

typedef unsigned int uint;
typedef unsigned short ushort;

__device__ __forceinline__ float sigm(float v) { return 1.f / (1.f + __expf(-v)); }

// round-to-nearest-even fp32 -> bf16 pair packed in a dword (lo = first elem)
__device__ __forceinline__ uint pack2(float a, float b) {
  uint ua = __float_as_uint(a), ub = __float_as_uint(b);
  ua = (ua + 0x7FFFu + ((ua >> 16) & 1u)) >> 16;
  ub = (ub + 0x7FFFu + ((ub >> 16) & 1u)) >> 16;
  return ua | (ub << 16);
}

__device__ __forceinline__ void unpk(uint d, float& lo, float& hi) {
  lo = __uint_as_float(d << 16);
  hi = __uint_as_float(d & 0xFFFF0000u);
}

struct Q { float4 a, b, c, d; };

// staging mode for (stream sL, chunk c) at step s:
// 0 = nothing, 1 = bf16 row copy, 2 = zero-fill, 3 = x fp32->bf16 convert
__device__ __forceinline__ int st_mode(int sL, int c, int s) {
  if (sL == 0) {
    if (s >= T_LEN || c >= 12) return 0;
    if (c < 8) return (s == 0) ? 2 : 1;
    return 3;
  } else {
    if (s < 1) return 0;
    if (c < 8) return (s == 1) ? 2 : 1;
    return 1;                       // y-part: layer-0 output (h0b_r)
  }
}

__device__ __forceinline__ void st_issue(Q& q, int sL, int c, int s,
    const ushort* __restrict__ h0b_r, const ushort* __restrict__ h1b_r,
    const float* __restrict__ x, int gb, int r) {
  const int m = st_mode(sL, c, s);
  if (m == 1) {
    const ushort* src = (sL == 0) ? (h0b_r + (size_t)gb * 512 + c * 64 + r * 16)
                   : (c < 8)      ? (h1b_r + (size_t)gb * 512 + c * 64 + r * 16)
                                  : (h0b_r + (size_t)gb * 512 + (c - 8) * 64 + r * 16);
    q.a = *(const float4*)src;
    q.b = *(const float4*)(src + 8);
  } else if (m == 2) {
    q.a = make_float4(0.f, 0.f, 0.f, 0.f);
    q.b = q.a;
  } else if (m == 3) {
    const float* src = x + (size_t)gb * (T_LEN * F_IN) + (size_t)s * F_IN
                         + (c - 8) * 64 + r * 16;
    q.a = *(const float4*)src;       q.b = *(const float4*)(src + 4);
    q.c = *(const float4*)(src + 8); q.d = *(const float4*)(src + 12);
  }
}

__device__ __forceinline__ void st_commit(const Q& q, float* __restrict__ lds,
                                          int sL, int c, int s, int b, int r) {
  const int m = st_mode(sL, c, s);
  if (m == 0) return;
  float* dst = lds + SBUF_OFF + (sL * 2 + (c & 1)) * 2304 + b * 36 + r * 8;
  if (m == 3) {
    uint4 pa, pb;
    pa.x = pack2(q.a.x, q.a.y); pa.y = pack2(q.a.z, q.a.w);
    pa.z = pack2(q.b.x, q.b.y); pa.w = pack2(q.b.z, q.b.w);
    pb.x = pack2(q.c.x, q.c.y); pb.y = pack2(q.c.z, q.c.w);
    pb.z = pack2(q.d.x, q.d.y); pb.w = pack2(q.d.z, q.d.w);
    *(uint4*)dst = pa; *(uint4*)(dst + 4) = pb;
  } else {
    *(float4*)dst = q.a; *(float4*)(dst + 4) = q.b;
  }
}

#define FMA16(A)                                                     \
  A = fmaf(w0.x, hv[0], A);  A = fmaf(w0.y, hv[1], A);               \
  A = fmaf(w0.z, hv[2], A);  A = fmaf(w0.w, hv[3], A);               \
  A = fmaf(w1.x, hv[4], A);  A = fmaf(w1.y, hv[5], A);               \
  A = fmaf(w1.z, hv[6], A);  A = fmaf(w1.w, hv[7], A);               \
  A = fmaf(w2.x, hv[8], A);  A = fmaf(w2.y, hv[9], A);               \
  A = fmaf(w2.z, hv[10], A); A = fmaf(w2.w, hv[11], A);              \
  A = fmaf(w3.x, hv[12], A); A = fmaf(w3.y, hv[13], A);              \
  A = fmaf(w3.z, hv[14], A); A = fmaf(w3.w, hv[15], A);

// one 16-k slice of chunk c for this wave's 12 rows.
// XPART=1: gi==2 rows accumulate into accx (input-projection part of n-gate).
template<int XPART>
__device__ __forceinline__ void chunk_fma(const float* __restrict__ lds,
    int sL, int c, int ch, int lane, float (&acc)[12], float (&accx)[4]) {
  const float* sb = lds + SBUF_OFF + (sL * 2 + (c & 1)) * 2304 + lane * 36 + ch * 8;
  const float4 r0 = *(const float4*)sb;
  const float4 r1 = *(const float4*)(sb + 4);
  float hv[16];
  unpk(__float_as_uint(r0.x), hv[0],  hv[1]);
  unpk(__float_as_uint(r0.y), hv[2],  hv[3]);
  unpk(__float_as_uint(r0.z), hv[4],  hv[5]);
  unpk(__float_as_uint(r0.w), hv[6],  hv[7]);
  unpk(__float_as_uint(r1.x), hv[8],  hv[9]);
  unpk(__float_as_uint(r1.y), hv[10], hv[11]);
  unpk(__float_as_uint(r1.z), hv[12], hv[13]);
  unpk(__float_as_uint(r1.w), hv[14], hv[15]);
  const int RL = sL ? 1024 : 768;
  const float* wbase = lds + (sL ? WL1_OFF : WL0_OFF) + c * 64 + ch * 16;
  #pragma unroll
  for (int jl = 0; jl < 4; ++jl) {
    #pragma unroll
    for (int gi = 0; gi < 3; ++gi) {
      const float* wr = wbase + (jl * 3 + gi) * RL;
      const float4 w0 = *(const float4*)wr;
      const float4 w1 = *(const float4*)(wr + 4);
      const float4 w2 = *(const float4*)(wr + 8);
      const float4 w3 = *(const float4*)(wr + 12);
      if (XPART && gi == 2) { float a = accx[jl];        FMA16(a); accx[jl] = a; }
      else                  { float a = acc[jl * 3 + gi]; FMA16(a); acc[jl * 3 + gi] = a; }
    }
  }
}

// Grid 256 = (batch-group 0..1) x (j-quad 0..127). Block 512 = 8 waves:
// wave = (sL = w>>2: 0 -> layer0@t=s, 1 -> layer1@t=s-1; ch = w&3: k-quarter).
__global__ void __launch_bounds__(512, 2)
gru_step(int s,
         const float* __restrict__ x,
         const float* __restrict__ Wih0, const float* __restrict__ Whh0,
         const float* __restrict__ bih0, const float* __restrict__ bhh0,
         const float* __restrict__ Wih1, const float* __restrict__ Whh1,
         const float* __restrict__ bih1, const float* __restrict__ bhh1,
         const float* __restrict__ h0f_r, float* __restrict__ h0f_w,
         const float* __restrict__ h1f_r, float* __restrict__ h1f_w,
         const ushort* __restrict__ h0b_r, ushort* __restrict__ h0b_w,
         const ushort* __restrict__ h1b_r, ushort* __restrict__ h1b_w)
{
  extern __shared__ float lds[];
  const int tid  = threadIdx.x;
  const int wave = tid >> 6;
  const int lane = tid & 63;
  const int sL   = wave >> 2;
  const int ch   = wave & 3;
  const int g    = blockIdx.x >> 7;
  const int j0   = (blockIdx.x & 127) << 2;
  const int b0   = g << 6;
  // staging role (independent of wave role)
  const int st_s  = tid >> 8;
  const int st_b  = (tid >> 2) & 63;
  const int st_r  = tid & 3;
  const int st_gb = b0 + st_b;

  const bool l0_act = (s < T_LEN);
  const bool l1_act = (s >= 1);

  // ---- weights -> LDS ----------------------------------------------------
  for (int i = tid; i < 2304; i += 512) {          // L0: 12 x 768
    const int row = i / 192, c4 = (i % 192) << 2;
    const int jl = row / 3, gi = row % 3;
    const int grow = gi * 512 + j0 + jl;
    const float4 v = (c4 < 512)
        ? *(const float4*)(Whh0 + (size_t)grow * 512 + c4)
        : *(const float4*)(Wih0 + (size_t)grow * 256 + (c4 - 512));
    *(float4*)(lds + WL0_OFF + row * 768 + c4) = v;
  }
  for (int i = tid; i < 3072; i += 512) {          // L1: 12 x 1024
    const int row = i >> 8, c4 = (i & 255) << 2;
    const int jl = row / 3, gi = row % 3;
    const int grow = gi * 512 + j0 + jl;
    const float4 v = (c4 < 512)
        ? *(const float4*)(Whh1 + (size_t)grow * 512 + c4)
        : *(const float4*)(Wih1 + (size_t)grow * 512 + (c4 - 512));
    *(float4*)(lds + WL1_OFF + row * 1024 + c4) = v;
  }

  // ---- state chunk pipeline prologue ------------------------------------
  Q q;
  st_issue(q, st_s, 0, s, h0b_r, h1b_r, x, st_gb, st_r);
  st_commit(q, lds, st_s, 0, s, st_b, st_r);
  st_issue(q, st_s, 1, s, h0b_r, h1b_r, x, st_gb, st_r);
  __syncthreads();

  float acc[12];
  #pragma unroll
  for (int i = 0; i < 12; ++i) acc[i] = 0.f;
  float accx[4] = {0.f, 0.f, 0.f, 0.f};
  const bool wact = sL ? l1_act : l0_act;

  // ---- main chunk loop ---------------------------------------------------
  for (int c = 0; c < NCH; ++c) {
    if (wact && (sL == 1 || c < 12)) {
      if (c < 8) chunk_fma<0>(lds, sL, c, ch, lane, acc, accx);
      else       chunk_fma<1>(lds, sL, c, ch, lane, acc, accx);
    }
    if (c + 1 < NCH) {
      st_commit(q, lds, st_s, c + 1, s, st_b, st_r);
      if (c + 2 < NCH)
        st_issue(q, st_s, c + 2, s, h0b_r, h1b_r, x, st_gb, st_r);
    }
    __syncthreads();
  }

  // ---- k-quarter reduction ----------------------------------------------
  if (wact && ch != 0) {
    float* rb = lds + RED_OFF + ((sL * 3 + (ch - 1)) * 16) * 64 + lane;
    #pragma unroll
    for (int i = 0; i < 12; ++i) rb[i * 64] = acc[i];
    #pragma unroll
    for (int i = 0; i < 4; ++i) rb[(12 + i) * 64] = accx[i];
  }
  __syncthreads();

  if (ch == 0 && wact) {
    #pragma unroll
    for (int p = 0; p < 3; ++p) {
      const float* rb = lds + RED_OFF + ((sL * 3 + p) * 16) * 64 + lane;
      #pragma unroll
      for (int i = 0; i < 12; ++i) acc[i] += rb[i * 64];
      #pragma unroll
      for (int i = 0; i < 4; ++i) accx[i] += rb[(12 + i) * 64];
    }
    // ---- epilogue --------------------------------------------------------
    const float* bi  = sL ? bih1 : bih0;
    const float* bh  = sL ? bhh1 : bhh0;
    const float* hpf = sL ? h1f_r : h0f_r;
    float*       hwf = sL ? h1f_w : h0f_w;
    ushort*      hwb = sL ? h1b_w : h0b_w;
    const bool hv_ok = sL ? (s >= 2) : (s >= 1);
    const int  gb    = b0 + lane;
    float hn[4];
    #pragma unroll
    for (int jl = 0; jl < 4; ++jl) {
      const int j = j0 + jl;
      const float pr = acc[jl * 3 + 0] + bi[j] + bh[j];
      const float pz = acc[jl * 3 + 1] + bi[512 + j] + bh[512 + j];
      const float phn = acc[jl * 3 + 2] + bh[1024 + j];
      const float pxn = accx[jl] + bi[1024 + j];
      const float r = sigm(pr);
      const float z = sigm(pz);
      const float n = tanhf(pxn + r * phn);
      const float hp = hv_ok ? hpf[j * 128 + gb] : 0.f;
      hn[jl] = (1.f - z) * n + z * hp;
      hwf[j * 128 + gb] = hn[jl];
    }
    uint2 pk;
    pk.x = pack2(hn[0], hn[1]);
    pk.y = pack2(hn[2], hn[3]);
    *(uint2*)(hwb + (size_t)gb * 512 + j0) = pk;
  }
}

// out[b] = sum_j h1f[j][b] * wlin[j] + blin[0];  h1f is fp32 [512 j][128 b]
__global__ void __launch_bounds__(512)
final_linear(const float* __restrict__ h1f, const float* __restrict__ wlin,
             const float* __restrict__ blin, float* __restrict__ out)
{
  __shared__ float red[4][B_SZ];
  const int b  = threadIdx.x & 127;
  const int jq = threadIdx.x >> 7;
  float acc = 0.f;
  #pragma unroll 8
  for (int j = jq * 128; j < jq * 128 + 128; ++j)
    acc = fmaf(h1f[j * 128 + b], wlin[j], acc);
  red[jq][b] = acc;
  __syncthreads();
  if (jq == 0)
    out[b] = red[0][b] + red[1][b] + red[2][b] + red[3][b] + blin[0];
}

extern "C" void kernel_launch(void* const* d_in, const int* in_sizes, int n_in,
                              void* d_out, int out_size, void* d_ws, size_t ws_size,
                              hipStream_t stream) {
  const float* x    = (const float*)d_in[0];
  const float* Wih0 = (const float*)d_in[1];
  const float* Whh0 = (const float*)d_in[2];
  const float* bih0 = (const float*)d_in[3];
  const float* bhh0 = (const float*)d_in[4];
  const float* Wih1 = (const float*)d_in[5];
  const float* Whh1 = (const float*)d_in[6];
  const float* bih1 = (const float*)d_in[7];
  const float* bhh1 = (const float*)d_in[8];
  const float* Wlin = (const float*)d_in[9];
  const float* blin = (const float*)d_in[10];

  // ws: fp32 h ping-pong [512 j][128 b] x4 (1 MB) + bf16 h [128 b][512 k] x4 (512 KB)
  float* ws = (float*)d_ws;
  float* h0f[2] = { ws,          ws + 65536 };
  float* h1f[2] = { ws + 131072, ws + 196608 };
  ushort* wsb = (ushort*)(ws + 262144);
  ushort* h0b[2] = { wsb,          wsb + 65536 };
  ushort* h1b[2] = { wsb + 131072, wsb + 196608 };

  static int attr_done = 0;   // idempotent, capture-safe (not a stream op)
  if (!attr_done) {
    hipFuncSetAttribute((const void*)gru_step,
                        hipFuncAttributeMaxDynamicSharedMemorySize, LDS_BYTES);
    attr_done = 1;
  }

  for (int s = 0; s <= T_LEN; ++s) {
    const int rp = s & 1, wp = rp ^ 1;
    gru_step<<<dim3(256), dim3(512), LDS_BYTES, stream>>>(
        s, x, Wih0, Whh0, bih0, bhh0, Wih1, Whh1, bih1, bhh1,
        h0f[rp], h0f[wp], h1f[rp], h1f[wp],
        h0b[rp], h0b[wp], h1b[rp], h1b[wp]);
  }
  // L1 @ t=1023 computed at s=1024, written to parity (1024+1)&1 = 1.
  final_linear<<<dim3(1), dim3(512), 0, stream>>>(h1f[1], Wlin, blin, (float*)d_out);
}